// Round 5
// baseline (147.822 us; speedup 1.0000x reference)
//
#include <hip/hip_runtime.h>

// Problem constants (compile-time, from reference):
//   B=2, D=H=W=160, C=2, N_LABELS=25, MAX_LABEL=48
//   voxels/batch V = 160^3 = 4,096,000 ; total voxels = 8,192,000
#define VPB   4096000
#define NLAB  25
#define MAXL  48

// Inverse LUT: FreeSurfer label value -> row index in means/stds.
// GEN_LABELS = {0,2,3,4,5,7,8,10,11,12,13,14,15,16,17,18,24,26,28,41,42,43,44,46,47}
__device__ __constant__ int c_lut[MAXL] = {
    /* 0*/ 0, /* 1*/ 0, /* 2*/ 1, /* 3*/ 2, /* 4*/ 3, /* 5*/ 4, /* 6*/ 0, /* 7*/ 5,
    /* 8*/ 6, /* 9*/ 0, /*10*/ 7, /*11*/ 8, /*12*/ 9, /*13*/10, /*14*/11, /*15*/12,
    /*16*/13, /*17*/14, /*18*/15, /*19*/ 0, /*20*/ 0, /*21*/ 0, /*22*/ 0, /*23*/ 0,
    /*24*/16, /*25*/ 0, /*26*/17, /*27*/ 0, /*28*/18, /*29*/ 0, /*30*/ 0, /*31*/ 0,
    /*32*/ 0, /*33*/ 0, /*34*/ 0, /*35*/ 0, /*36*/ 0, /*37*/ 0, /*38*/ 0, /*39*/ 0,
    /*40*/ 0, /*41*/19, /*42*/20, /*43*/21, /*44*/22, /*45*/ 0, /*46**/23, /*47*/24
};

// Persistent full-residency grid: 2000 blocks x 256 threads (~8 blocks/CU =
// 32 waves/CU). Each thread does 8 voxels of batch 0 and the mirrored 8
// voxels of batch 1 (2000*256*8 = 4,096,000 = exactly one batch) — no tail,
// no churn, batch offset is compile-time per half.
// Round-3 lesson: NO nontemporal stores (1.74x WRITE_SIZE amplification).
__global__ __launch_bounds__(256, 8) void gmm_sample_kernel(
    const int*   __restrict__ labels,   // [B*V] (trailing dim 1 squeezed)
    const float* __restrict__ means,    // [B, 25, 2]
    const float* __restrict__ stds,     // [B, 25, 2]
    const float* __restrict__ noise,    // [B*V, 2]
    float*       __restrict__ out)      // [B*V, 2]
{
    // Fused per-(batch,label-value) table: (mean0, mean1, std0, std1).
    __shared__ float4 table[2 * MAXL];

    const int tid = threadIdx.x;
    if (tid < 2 * MAXL) {
        const int b = tid / MAXL;
        const int v = tid - b * MAXL;
        const int row = c_lut[v];
        const float* mp = means + ((b * NLAB + row) << 1);
        const float* sp = stds  + ((b * NLAB + row) << 1);
        table[tid] = make_float4(mp[0], mp[1], sp[0], sp[1]);
    }
    __syncthreads();

    const int g = blockIdx.x * 256 + tid;           // thread id, < 512,000
    const long long v0 = (long long)g << 3;         // batch-0 voxel base
    const long long v1 = v0 + VPB;                  // batch-1 voxel base

    // Issue ALL global loads up front: 192 B/lane in flight.
    const int4* lp0 = (const int4*)(labels + v0);
    const int4* lp1 = (const int4*)(labels + v1);
    const int4 la0 = lp0[0];
    const int4 lb0 = lp0[1];
    const int4 la1 = lp1[0];
    const int4 lb1 = lp1[1];

    const float4* np0 = (const float4*)(noise + (v0 << 1));
    const float4* np1 = (const float4*)(noise + (v1 << 1));
    const float4 n0 = np0[0];
    const float4 n1 = np0[1];
    const float4 n2 = np0[2];
    const float4 n3 = np0[3];
    const float4 m0 = np1[0];
    const float4 m1 = np1[1];
    const float4 m2 = np1[2];
    const float4 m3 = np1[3];

    // ---- batch 0 half ----
    {
        const float4 e0 = table[la0.x];
        const float4 e1 = table[la0.y];
        const float4 e2 = table[la0.z];
        const float4 e3 = table[la0.w];
        const float4 e4 = table[lb0.x];
        const float4 e5 = table[lb0.y];
        const float4 e6 = table[lb0.z];
        const float4 e7 = table[lb0.w];

        float4 o0, o1, o2, o3;
        o0.x = fmaf(e0.z, n0.x, e0.x);
        o0.y = fmaf(e0.w, n0.y, e0.y);
        o0.z = fmaf(e1.z, n0.z, e1.x);
        o0.w = fmaf(e1.w, n0.w, e1.y);
        o1.x = fmaf(e2.z, n1.x, e2.x);
        o1.y = fmaf(e2.w, n1.y, e2.y);
        o1.z = fmaf(e3.z, n1.z, e3.x);
        o1.w = fmaf(e3.w, n1.w, e3.y);
        o2.x = fmaf(e4.z, n2.x, e4.x);
        o2.y = fmaf(e4.w, n2.y, e4.y);
        o2.z = fmaf(e5.z, n2.z, e5.x);
        o2.w = fmaf(e5.w, n2.w, e5.y);
        o3.x = fmaf(e6.z, n3.x, e6.x);
        o3.y = fmaf(e6.w, n3.y, e6.y);
        o3.z = fmaf(e7.z, n3.z, e7.x);
        o3.w = fmaf(e7.w, n3.w, e7.y);

        float4* op = (float4*)(out + (v0 << 1));
        op[0] = o0;
        op[1] = o1;
        op[2] = o2;
        op[3] = o3;
    }

    // ---- batch 1 half ----
    {
        const float4 e0 = table[MAXL + la1.x];
        const float4 e1 = table[MAXL + la1.y];
        const float4 e2 = table[MAXL + la1.z];
        const float4 e3 = table[MAXL + la1.w];
        const float4 e4 = table[MAXL + lb1.x];
        const float4 e5 = table[MAXL + lb1.y];
        const float4 e6 = table[MAXL + lb1.z];
        const float4 e7 = table[MAXL + lb1.w];

        float4 o0, o1, o2, o3;
        o0.x = fmaf(e0.z, m0.x, e0.x);
        o0.y = fmaf(e0.w, m0.y, e0.y);
        o0.z = fmaf(e1.z, m0.z, e1.x);
        o0.w = fmaf(e1.w, m0.w, e1.y);
        o1.x = fmaf(e2.z, m1.x, e2.x);
        o1.y = fmaf(e2.w, m1.y, e2.y);
        o1.z = fmaf(e3.z, m1.z, e3.x);
        o1.w = fmaf(e3.w, m1.w, e3.y);
        o2.x = fmaf(e4.z, m2.x, e4.x);
        o2.y = fmaf(e4.w, m2.y, e4.y);
        o2.z = fmaf(e5.z, m2.z, e5.x);
        o2.w = fmaf(e5.w, m2.w, e5.y);
        o3.x = fmaf(e6.z, m3.x, e6.x);
        o3.y = fmaf(e6.w, m3.y, e6.y);
        o3.z = fmaf(e7.z, m3.z, e7.x);
        o3.w = fmaf(e7.w, m3.w, e7.y);

        float4* op = (float4*)(out + (v1 << 1));
        op[0] = o0;
        op[1] = o1;
        op[2] = o2;
        op[3] = o3;
    }
}

extern "C" void kernel_launch(void* const* d_in, const int* in_sizes, int n_in,
                              void* d_out, int out_size, void* d_ws, size_t ws_size,
                              hipStream_t stream) {
    const int*   labels = (const int*)  d_in[0];  // [2,160,160,160,1] int32
    const float* means  = (const float*)d_in[1];  // [2,25,2] f32
    const float* stds   = (const float*)d_in[2];  // [2,25,2] f32
    const float* noise  = (const float*)d_in[3];  // [2,160,160,160,2] f32
    float* out = (float*)d_out;                   // [2,160,160,160,2] f32

    const int threads = 256;
    const int blocks = VPB / (threads * 8);       // 2000
    gmm_sample_kernel<<<blocks, threads, 0, stream>>>(labels, means, stds, noise, out);
}

// Round 6
// 142.115 us; speedup vs baseline: 1.0402x; 1.0402x over previous
//
#include <hip/hip_runtime.h>

// Problem constants (compile-time, from reference):
//   B=2, D=H=W=160, C=2, N_LABELS=25, MAX_LABEL=48
//   voxels/batch V = 160^3 = 4,096,000 ; total voxels = 8,192,000
#define VPB   4096000
#define NLAB  25
#define MAXL  48
#define TOTAL_VOX 8192000

// Inverse LUT: FreeSurfer label value -> row index in means/stds.
// GEN_LABELS = {0,2,3,4,5,7,8,10,11,12,13,14,15,16,17,18,24,26,28,41,42,43,44,46,47}
__device__ __constant__ int c_lut[MAXL] = {
    /* 0*/ 0, /* 1*/ 0, /* 2*/ 1, /* 3*/ 2, /* 4*/ 3, /* 5*/ 4, /* 6*/ 0, /* 7*/ 5,
    /* 8*/ 6, /* 9*/ 0, /*10*/ 7, /*11*/ 8, /*12*/ 9, /*13*/10, /*14*/11, /*15*/12,
    /*16*/13, /*17*/14, /*18*/15, /*19*/ 0, /*20*/ 0, /*21*/ 0, /*22*/ 0, /*23*/ 0,
    /*24*/16, /*25*/ 0, /*26*/17, /*27*/ 0, /*28*/18, /*29*/ 0, /*30*/ 0, /*31*/ 0,
    /*32*/ 0, /*33*/ 0, /*34*/ 0, /*35*/ 0, /*36*/ 0, /*37*/ 0, /*38*/ 0, /*39*/ 0,
    /*40*/ 0, /*41*/19, /*42*/20, /*43*/21, /*44*/22, /*45*/ 0, /*46*/23, /*47*/24
};

// One thread handles 4 consecutive voxels. Grid: 8000 x 256 (best measured
// granularity — larger per-thread tiles regressed in r4/r5).
// Round-3 lesson: NO nontemporal stores (1.74x WRITE_SIZE amplification).
// Round-6 change: global loads issued BEFORE the table build + barrier so
// load latency overlaps the prologue (compiler can't hoist across barrier).
__global__ __launch_bounds__(256) void gmm_sample_kernel(
    const int*   __restrict__ labels,   // [B*V] (trailing dim 1 squeezed)
    const float* __restrict__ means,    // [B, 25, 2]
    const float* __restrict__ stds,     // [B, 25, 2]
    const float* __restrict__ noise,    // [B*V, 2]
    float*       __restrict__ out)      // [B*V, 2]
{
    __shared__ float4 table[2 * MAXL];

    const int tid = threadIdx.x;
    const int g  = blockIdx.x * 256 + tid;      // thread id, < 2,048,000
    const int v0 = g << 2;                      // first voxel, < 8,192,000

    // ---- issue global loads FIRST: in flight during table build + barrier ----
    const int4   lab = *(const int4*)  (labels + v0);
    const float4 n0  = *(const float4*)(noise + ((size_t)v0 << 1));
    const float4 n1  = *(const float4*)(noise + ((size_t)v0 << 1) + 4);

    // ---- fused per-(batch,label-value) table: (mean0, mean1, std0, std1) ----
    if (tid < 2 * MAXL) {
        const int b = tid / MAXL;
        const int v = tid - b * MAXL;
        const int row = c_lut[v];
        const float* mp = means + ((b * NLAB + row) << 1);
        const float* sp = stds  + ((b * NLAB + row) << 1);
        table[tid] = make_float4(mp[0], mp[1], sp[0], sp[1]);
    }
    __syncthreads();

    // Batch boundary (4,096,000) is a multiple of 4 -> all 4 voxels same batch.
    const int boff = (v0 >= VPB) ? MAXL : 0;

    const float4 e0 = table[boff + lab.x];
    const float4 e1 = table[boff + lab.y];
    const float4 e2 = table[boff + lab.z];
    const float4 e3 = table[boff + lab.w];

    float4 o0, o1;
    o0.x = fmaf(e0.z, n0.x, e0.x);
    o0.y = fmaf(e0.w, n0.y, e0.y);
    o0.z = fmaf(e1.z, n0.z, e1.x);
    o0.w = fmaf(e1.w, n0.w, e1.y);
    o1.x = fmaf(e2.z, n1.x, e2.x);
    o1.y = fmaf(e2.w, n1.y, e2.y);
    o1.z = fmaf(e3.z, n1.z, e3.x);
    o1.w = fmaf(e3.w, n1.w, e3.y);

    *(float4*)(out + ((size_t)v0 << 1))     = o0;
    *(float4*)(out + ((size_t)v0 << 1) + 4) = o1;
}

extern "C" void kernel_launch(void* const* d_in, const int* in_sizes, int n_in,
                              void* d_out, int out_size, void* d_ws, size_t ws_size,
                              hipStream_t stream) {
    const int*   labels = (const int*)  d_in[0];  // [2,160,160,160,1] int32
    const float* means  = (const float*)d_in[1];  // [2,25,2] f32
    const float* stds   = (const float*)d_in[2];  // [2,25,2] f32
    const float* noise  = (const float*)d_in[3];  // [2,160,160,160,2] f32
    float* out = (float*)d_out;                   // [2,160,160,160,2] f32

    const int threads = 256;
    const int total_threads = TOTAL_VOX / 4;      // 2,048,000
    const int blocks = total_threads / threads;   // 8000
    gmm_sample_kernel<<<blocks, threads, 0, stream>>>(labels, means, stds, noise, out);
}